// Round 1
// baseline (876.789 us; speedup 1.0000x reference)
//
#include <hip/hip_runtime.h>
#include <hip/hip_bf16.h>
#include <stdint.h>

#define NH 16
#define HD 64
#define DM 1024
#define NB 4
#define SEQ 1024
#define NTOK (NB*SEQ)
#define SCALE 0.125f

typedef __bf16 bf16_t;
typedef __bf16 bf16x8 __attribute__((ext_vector_type(8)));
typedef __bf16 bf16x4 __attribute__((ext_vector_type(4)));
typedef float f32x4 __attribute__((ext_vector_type(4)));
typedef float f32x2 __attribute__((ext_vector_type(2)));

// ---------------- fp32 -> bf16 convert (hidden_states) ----------------
__global__ void cvt_hs_kernel(const float* __restrict__ in, bf16_t* __restrict__ out, int n4){
  int i = blockIdx.x*256 + threadIdx.x;
  if (i >= n4) return;
  f32x4 v = ((const f32x4*)in)[i];
  bf16x4 o;
  o[0]=(bf16_t)v[0]; o[1]=(bf16_t)v[1]; o[2]=(bf16_t)v[2]; o[3]=(bf16_t)v[3];
  ((bf16x4*)out)[i] = o;
}

// ------------- W transpose + convert: Wt[n][k] = W[k][n] (bf16) -------------
__global__ void cvt_wt_kernel(const float* __restrict__ Wq, const float* __restrict__ Wk,
                              const float* __restrict__ Wv, bf16_t* __restrict__ outbase){
  __shared__ float tile[32][33];
  const float* W = blockIdx.z==0 ? Wq : (blockIdx.z==1 ? Wk : Wv);
  bf16_t* Wt = outbase + (size_t)blockIdx.z * DM * DM;
  int k0 = blockIdx.x*32, n0 = blockIdx.y*32;
  #pragma unroll
  for (int i=0;i<4;i++){
    int r = threadIdx.y + i*8;
    tile[r][threadIdx.x] = W[(size_t)(k0+r)*DM + n0 + threadIdx.x];
  }
  __syncthreads();
  #pragma unroll
  for (int i=0;i<4;i++){
    int r = threadIdx.y + i*8;
    Wt[(size_t)(n0+r)*DM + k0 + threadIdx.x] = (bf16_t)tile[threadIdx.x][r];
  }
}

// ---------------- QKV GEMM: bf16 MFMA, C = hs @ W + b -> [B,H,S,HD] fp32 ----------------
// A: hsb [4096][1024] bf16 row-major; B: Wt [n][k] bf16 (i.e. W^T)
// Tile 128x128x64, 4 waves (2x2), each wave 64x64 via 4x4 frags of 16x16x32.
__global__ __launch_bounds__(256)
void qkv_gemm_kernel(const bf16_t* __restrict__ Ag, const bf16_t* __restrict__ Wtb,
                     const float* __restrict__ bq, const float* __restrict__ bk, const float* __restrict__ bv,
                     float* __restrict__ Qb, float* __restrict__ Kb, float* __restrict__ Vb)
{
  __shared__ __align__(16) bf16_t Asm[128*64];
  __shared__ __align__(16) bf16_t Bsm[128*64];
  const int z = blockIdx.z;
  const bf16_t* Btg = Wtb + (size_t)z*DM*DM;
  const float* bias = (z==0)?bq:((z==1)?bk:bv);
  float* dst = (z==0)?Qb:((z==1)?Kb:Vb);
  const int m0 = blockIdx.x*128, n0 = blockIdx.y*128;
  const int tid = threadIdx.x, lane = tid&63, w = tid>>6;
  const int wr = w>>1, wc = w&1;
  const int lr = lane&15, hk = (lane>>4)<<3;

  f32x4 acc[4][4];
  #pragma unroll
  for (int a=0;a<4;a++)
    #pragma unroll
    for (int c=0;c<4;c++)
      acc[a][c] = (f32x4){0.f,0.f,0.f,0.f};

  for (int k0=0; k0<DM; k0+=64){
    // reg-staged global->LDS (16B per thread-iter), linear row-major [row][64] bf16
    #pragma unroll
    for (int i=0;i<4;i++){
      int flat = i*256 + tid;          // 0..1023 chunks of 16B
      int row = flat>>3, kc = (flat&7)<<3;
      *(bf16x8*)&Asm[(row<<6)+kc] = *(const bf16x8*)&Ag [(size_t)(m0+row)*DM + k0 + kc];
      *(bf16x8*)&Bsm[(row<<6)+kc] = *(const bf16x8*)&Btg[(size_t)(n0+row)*DM + k0 + kc];
    }
    __syncthreads();
    #pragma unroll
    for (int kk=0;kk<2;kk++){
      bf16x8 af[4], bfv[4];
      #pragma unroll
      for (int mf=0;mf<4;mf++)
        af[mf] = *(const bf16x8*)&Asm[((wr*64 + mf*16 + lr)<<6) + (kk<<5) + hk];
      #pragma unroll
      for (int nf=0;nf<4;nf++)
        bfv[nf] = *(const bf16x8*)&Bsm[((wc*64 + nf*16 + lr)<<6) + (kk<<5) + hk];
      #pragma unroll
      for (int mf=0;mf<4;mf++)
        #pragma unroll
        for (int nf=0;nf<4;nf++)
          acc[mf][nf] = __builtin_amdgcn_mfma_f32_16x16x32_bf16(af[mf], bfv[nf], acc[mf][nf], 0, 0, 0);
    }
    __syncthreads();
  }

  // epilogue: +bias, scatter to [B,H,S,HD] fp32
  #pragma unroll
  for (int mf=0;mf<4;mf++){
    #pragma unroll
    for (int nf=0;nf<4;nf++){
      int gn = n0 + wc*64 + nf*16 + lr;
      float bsv = bias[gn];
      int hh = gn>>6, hd = gn&63;
      #pragma unroll
      for (int j=0;j<4;j++){
        int gm = m0 + wr*64 + mf*16 + ((lane>>4)<<2) + j;
        int bb = gm>>10, sq = gm&1023;
        dst[(((size_t)bb*NH + hh)*SEQ + sq)*HD + hd] = acc[mf][nf][j] + bsv;
      }
    }
  }
}

// ---------------- wave reduction helpers ----------------
__device__ __forceinline__ float wsum(float v){
  #pragma unroll
  for (int m=32;m>=1;m>>=1) v += __shfl_xor(v, m, 64);
  return v;
}
__device__ __forceinline__ float wmax(float v){
  #pragma unroll
  for (int m=32;m>=1;m>>=1) v = fmaxf(v, __shfl_xor(v, m, 64));
  return v;
}

// ---------------- fused attention (fp32 vector), 8 waves x 4 rows ----------------
// scores: s[r][t] holds score for q-row (w*4+r), k-col (t*64+lane)
__global__ __launch_bounds__(512)
void attn_fused_kernel(const float* __restrict__ Qg, const float* __restrict__ Kg,
                       const float* __restrict__ Vg, const float* __restrict__ maskg,
                       float* __restrict__ outg)
{
  __shared__ __align__(16) float Ts[64*64];     // K/V tile, chunk-XOR-swizzled
  __shared__ __align__(16) float Qs[32][64];
  __shared__ __align__(16) float Ws[8][4][64];  // per-wave weight slice for PV
  __shared__ __align__(16) float Ms[1024];
  const int bh = blockIdx.y, b = bh>>4, h = bh&15;
  const int row0 = blockIdx.x*32;
  const int tid = threadIdx.x, lane = tid&63, w = tid>>6;
  const size_t hoff = (size_t)bh*SEQ*HD;
  const int rq = w<<2;

  { int r = tid>>4, c4 = (tid&15)<<2;
    *(f32x4*)&Qs[r][c4] = *(const f32x4*)&Qg[hoff + (size_t)(row0+r)*HD + c4]; }
  { int m2 = tid<<1;
    *(f32x2*)&Ms[m2] = *(const f32x2*)&maskg[(size_t)b*SEQ + m2]; }

  float s[4][16];

  // ---- phase 1: scores ----
  #pragma unroll
  for (int t=0;t<16;t++){
    __syncthreads();
    #pragma unroll
    for (int i=0;i<2;i++){
      int flat = i*512 + tid;          // 0..1023 float4 chunks
      int r = flat>>4, c = flat&15;
      f32x4 vv = *(const f32x4*)&Kg[hoff + (size_t)(t*64+r)*HD + (c<<2)];
      *(f32x4*)&Ts[(r<<6) + ((c ^ (r&7))<<2)] = vv;   // swizzled store
    }
    __syncthreads();
    float a0=0.f,a1=0.f,a2=0.f,a3=0.f;
    #pragma unroll
    for (int c=0;c<16;c++){
      f32x4 kv = *(const f32x4*)&Ts[(lane<<6) + ((c ^ (lane&7))<<2)];
      f32x4 q0 = *(const f32x4*)&Qs[rq+0][c<<2];
      f32x4 q1 = *(const f32x4*)&Qs[rq+1][c<<2];
      f32x4 q2 = *(const f32x4*)&Qs[rq+2][c<<2];
      f32x4 q3 = *(const f32x4*)&Qs[rq+3][c<<2];
      #pragma unroll
      for (int j=0;j<4;j++){
        a0 = fmaf(q0[j], kv[j], a0);
        a1 = fmaf(q1[j], kv[j], a1);
        a2 = fmaf(q2[j], kv[j], a2);
        a3 = fmaf(q3[j], kv[j], a3);
      }
    }
    s[0][t]=a0; s[1][t]=a1; s[2][t]=a2; s[3][t]=a3;
  }

  // ---- scale + mask + clamp ----
  #pragma unroll
  for (int t=0;t<16;t++){
    float mk = Ms[(t<<6) + lane];
    #pragma unroll
    for (int r=0;r<4;r++)
      s[r][t] = fmaxf(fmaf(s[r][t], SCALE, mk), -10000.0f);
  }

  // ---- sparsemax (even heads) / softmax (odd heads) ----
  if ((h&1)==0){
    #pragma unroll
    for (int r=0;r<4;r++){
      float mx = s[r][0];
      #pragma unroll
      for (int t=1;t<16;t++) mx = fmaxf(mx, s[r][t]);
      mx = wmax(mx);
      float lo = mx - 1.0f, hi = mx;
      for (int it=0; it<24; ++it){
        float mid = 0.5f*(lo+hi);
        float g = 0.f;
        #pragma unroll
        for (int t=0;t<16;t++) g += fmaxf(s[r][t]-mid, 0.0f);
        g = wsum(g);
        if (g >= 1.0f) lo = mid; else hi = mid;
      }
      float mid = 0.5f*(lo+hi);
      float cnt=0.f, sz=0.f;
      #pragma unroll
      for (int t=0;t<16;t++){
        if (s[r][t] > mid){ cnt += 1.0f; sz += s[r][t]; }
      }
      cnt = wsum(cnt); sz = wsum(sz);
      float tau = (sz - 1.0f) / cnt;
      #pragma unroll
      for (int t=0;t<16;t++) s[r][t] = fmaxf(s[r][t]-tau, 0.0f);
    }
  } else {
    #pragma unroll
    for (int r=0;r<4;r++){
      float mx = s[r][0];
      #pragma unroll
      for (int t=1;t<16;t++) mx = fmaxf(mx, s[r][t]);
      mx = wmax(mx);
      float sum = 0.f;
      #pragma unroll
      for (int t=0;t<16;t++){ s[r][t] = __expf(s[r][t]-mx); sum += s[r][t]; }
      sum = wsum(sum);
      float inv = 1.0f/sum;
      #pragma unroll
      for (int t=0;t<16;t++) s[r][t] *= inv;
    }
  }

  // ---- phase 2: out = weights @ V ; lane = output dim ----
  float o0=0.f,o1=0.f,o2=0.f,o3=0.f;
  #pragma unroll
  for (int t=0;t<16;t++){
    __syncthreads();
    #pragma unroll
    for (int i=0;i<2;i++){
      int flat = i*512 + tid;
      int r = flat>>4, c = flat&15;
      f32x4 vv = *(const f32x4*)&Vg[hoff + (size_t)(t*64+r)*HD + (c<<2)];
      *(f32x4*)&Ts[(r<<6) + ((c ^ (r&7))<<2)] = vv;
    }
    Ws[w][0][lane] = s[0][t];
    Ws[w][1][lane] = s[1][t];
    Ws[w][2][lane] = s[2][t];
    Ws[w][3][lane] = s[3][t];
    __syncthreads();
    #pragma unroll
    for (int k4=0;k4<16;k4++){
      f32x4 w0 = *(const f32x4*)&Ws[w][0][k4<<2];
      f32x4 w1 = *(const f32x4*)&Ws[w][1][k4<<2];
      f32x4 w2 = *(const f32x4*)&Ws[w][2][k4<<2];
      f32x4 w3 = *(const f32x4*)&Ws[w][3][k4<<2];
      #pragma unroll
      for (int j=0;j<4;j++){
        int kk = (k4<<2)+j;
        float vv = Ts[(kk<<6) + (((lane>>2) ^ (kk&7))<<2) + (lane&3)];
        o0 = fmaf(w0[j], vv, o0);
        o1 = fmaf(w1[j], vv, o1);
        o2 = fmaf(w2[j], vv, o2);
        o3 = fmaf(w3[j], vv, o3);
      }
    }
  }

  size_t ob = ((size_t)(b*SEQ + row0 + rq))*(size_t)DM + (h<<6) + lane;
  outg[ob]        = o0;
  outg[ob + DM]   = o1;
  outg[ob + 2*DM] = o2;
  outg[ob + 3*DM] = o3;
}

// ---------------- launch ----------------
extern "C" void kernel_launch(void* const* d_in, const int* in_sizes, int n_in,
                              void* d_out, int out_size, void* d_ws, size_t ws_size,
                              hipStream_t stream)
{
  const float* hs   = (const float*)d_in[0];
  const float* Wq   = (const float*)d_in[1];
  const float* bq   = (const float*)d_in[2];
  const float* Wk   = (const float*)d_in[3];
  const float* bk   = (const float*)d_in[4];
  const float* Wv   = (const float*)d_in[5];
  const float* bv   = (const float*)d_in[6];
  const float* mask = (const float*)d_in[7];
  float* out = (float*)d_out;

  char* ws = (char*)d_ws;
  bf16_t* hsb = (bf16_t*)ws;                          // 8 MB
  bf16_t* Wt  = (bf16_t*)(ws + (size_t)(8u<<20));     // 6 MB (3 x 2MB)
  float*  Qb  = (float*)(ws + (size_t)(14u<<20));     // 16 MB each
  float*  Kb  = (float*)(ws + (size_t)(30u<<20));
  float*  Vb  = (float*)(ws + (size_t)(46u<<20));

  cvt_hs_kernel<<<(NTOK*DM/4 + 255)/256, 256, 0, stream>>>(hs, hsb, NTOK*DM/4);
  cvt_wt_kernel<<<dim3(32,32,3), dim3(32,8), 0, stream>>>(Wq, Wk, Wv, Wt);
  qkv_gemm_kernel<<<dim3(32,8,3), 256, 0, stream>>>(hsb, Wt, bq, bk, bv, Qb, Kb, Vb);
  attn_fused_kernel<<<dim3(32,64), 512, 0, stream>>>(Qb, Kb, Vb, mask, out);
}

// Round 2
// 332.326 us; speedup vs baseline: 2.6383x; 2.6383x over previous
//
#include <hip/hip_runtime.h>
#include <hip/hip_bf16.h>
#include <stdint.h>

#define NH 16
#define HD 64
#define DM 1024
#define NB 4
#define SEQ 1024
#define NTOK (NB*SEQ)
#define SCALE 0.125f

typedef __bf16 bf16_t;
typedef __bf16 bf16x8 __attribute__((ext_vector_type(8)));
typedef __bf16 bf16x4 __attribute__((ext_vector_type(4)));
typedef float f32x4 __attribute__((ext_vector_type(4)));
typedef float f32x2 __attribute__((ext_vector_type(2)));

// ---------------- fp32 -> bf16 convert (hidden_states) ----------------
__global__ void cvt_hs_kernel(const float* __restrict__ in, bf16_t* __restrict__ out, int n4){
  int i = blockIdx.x*256 + threadIdx.x;
  if (i >= n4) return;
  f32x4 v = ((const f32x4*)in)[i];
  bf16x4 o;
  o[0]=(bf16_t)v[0]; o[1]=(bf16_t)v[1]; o[2]=(bf16_t)v[2]; o[3]=(bf16_t)v[3];
  ((bf16x4*)out)[i] = o;
}

// ------------- W transpose + convert: Wt[n][k] = W[k][n] (bf16) -------------
__global__ void cvt_wt_kernel(const float* __restrict__ Wq, const float* __restrict__ Wk,
                              const float* __restrict__ Wv, bf16_t* __restrict__ outbase){
  __shared__ float tile[32][33];
  const float* W = blockIdx.z==0 ? Wq : (blockIdx.z==1 ? Wk : Wv);
  bf16_t* Wt = outbase + (size_t)blockIdx.z * DM * DM;
  int k0 = blockIdx.x*32, n0 = blockIdx.y*32;
  #pragma unroll
  for (int i=0;i<4;i++){
    int r = threadIdx.y + i*8;
    tile[r][threadIdx.x] = W[(size_t)(k0+r)*DM + n0 + threadIdx.x];
  }
  __syncthreads();
  #pragma unroll
  for (int i=0;i<4;i++){
    int r = threadIdx.y + i*8;
    Wt[(size_t)(n0+r)*DM + k0 + threadIdx.x] = (bf16_t)tile[threadIdx.x][r];
  }
}

// ---------------- QKV GEMM: bf16 MFMA, outputs bf16 ----------------
// Q,K -> [bh][seq][hd] bf16 ; V -> transposed [bh][hd][seq] bf16
__global__ __launch_bounds__(256)
void qkv_gemm_kernel(const bf16_t* __restrict__ Ag, const bf16_t* __restrict__ Wtb,
                     const float* __restrict__ bq, const float* __restrict__ bk, const float* __restrict__ bv,
                     bf16_t* __restrict__ Qb, bf16_t* __restrict__ Kb, bf16_t* __restrict__ Vtb)
{
  __shared__ __align__(16) bf16_t Asm[128*64];
  __shared__ __align__(16) bf16_t Bsm[128*64];
  const int z = blockIdx.z;
  const bf16_t* Btg = Wtb + (size_t)z*DM*DM;
  const float* bias = (z==0)?bq:((z==1)?bk:bv);
  const int m0 = blockIdx.x*128, n0 = blockIdx.y*128;
  const int tid = threadIdx.x, lane = tid&63, w = tid>>6;
  const int wr = w>>1, wc = w&1;
  const int lr = lane&15, hk = (lane>>4)<<3;

  f32x4 acc[4][4];
  #pragma unroll
  for (int a=0;a<4;a++)
    #pragma unroll
    for (int c=0;c<4;c++)
      acc[a][c] = (f32x4){0.f,0.f,0.f,0.f};

  for (int k0=0; k0<DM; k0+=64){
    #pragma unroll
    for (int i=0;i<4;i++){
      int flat = i*256 + tid;
      int row = flat>>3, kc = (flat&7)<<3;
      *(bf16x8*)&Asm[(row<<6)+kc] = *(const bf16x8*)&Ag [(size_t)(m0+row)*DM + k0 + kc];
      *(bf16x8*)&Bsm[(row<<6)+kc] = *(const bf16x8*)&Btg[(size_t)(n0+row)*DM + k0 + kc];
    }
    __syncthreads();
    #pragma unroll
    for (int kk=0;kk<2;kk++){
      bf16x8 af[4], bfv[4];
      #pragma unroll
      for (int mf=0;mf<4;mf++)
        af[mf] = *(const bf16x8*)&Asm[((wr*64 + mf*16 + lr)<<6) + (kk<<5) + hk];
      #pragma unroll
      for (int nf=0;nf<4;nf++)
        bfv[nf] = *(const bf16x8*)&Bsm[((wc*64 + nf*16 + lr)<<6) + (kk<<5) + hk];
      #pragma unroll
      for (int mf=0;mf<4;mf++)
        #pragma unroll
        for (int nf=0;nf<4;nf++)
          acc[mf][nf] = __builtin_amdgcn_mfma_f32_16x16x32_bf16(af[mf], bfv[nf], acc[mf][nf], 0, 0, 0);
    }
    __syncthreads();
  }

  const int q4 = (lane>>4)<<2;
  #pragma unroll
  for (int mf=0;mf<4;mf++){
    #pragma unroll
    for (int nf=0;nf<4;nf++){
      int gn = n0 + wc*64 + nf*16 + lr;
      float bsv = bias[gn];
      int hh = gn>>6, hd = gn&63;
      int gm0 = m0 + wr*64 + mf*16 + q4;
      int bb = gm0>>10, sq0 = gm0&1023;
      if (z < 2){
        bf16_t* dst = (z==0)?Qb:Kb;
        #pragma unroll
        for (int j=0;j<4;j++)
          dst[(((size_t)bb*NH + hh)*SEQ + (sq0+j))*HD + hd] = (bf16_t)(acc[mf][nf][j] + bsv);
      } else {
        bf16x4 pk;
        #pragma unroll
        for (int j=0;j<4;j++) pk[j] = (bf16_t)(acc[mf][nf][j] + bsv);
        *(bf16x4*)&Vtb[(((size_t)bb*NH + hh)*HD + hd)*SEQ + sq0] = pk;
      }
    }
  }
}

// ---------------- wave reduction helpers ----------------
__device__ __forceinline__ float wsum(float v){
  #pragma unroll
  for (int m=32;m>=1;m>>=1) v += __shfl_xor(v, m, 64);
  return v;
}
__device__ __forceinline__ float wmax(float v){
  #pragma unroll
  for (int m=32;m>=1;m>>=1) v = fmaxf(v, __shfl_xor(v, m, 64));
  return v;
}

// weight store with 16B-chunk XOR swizzle (PV A-frag ds_read_b128 conflict-free)
__device__ __forceinline__ void wstore(bf16_t* Wb, int row, int col, float v){
  int chunk = (col >> 3) ^ (row & 15);
  Wb[row*1024 + chunk*8 + (col&7)] = (bf16_t)v;
}

// ---------------- fused MFMA attention ----------------
// block: one (b,h) x 32 q-rows. 8 waves; wave w owns key-slice [w*128, w*128+128).
__global__ __launch_bounds__(512)
void attn_mfma_kernel(const bf16_t* __restrict__ Qg, const bf16_t* __restrict__ Kg,
                      const bf16_t* __restrict__ Vt, const float* __restrict__ maskg,
                      float* __restrict__ outg)
{
  __shared__ __align__(16) float S[32*1024];      // 128 KB scores
  bf16_t* Wlds = (bf16_t*)S;                       // aliases bytes [0,64K): weights 32x1024 bf16
  float*  Pacc = S + 16*1024;                      // aliases bytes [64K,128K): 8x32x64 partials

  const int bh = blockIdx.y, b = bh>>4, h = bh&15;
  const int row0 = blockIdx.x*32;
  const int tid = threadIdx.x, lane = tid&63, w = tid>>6;
  const int ln = lane&15, hi4 = lane>>4;           // 0..3
  const size_t hoff = (size_t)bh*SEQ*HD;
  const int k0w = w*128;

  // ---- Q fragments (A: row=lane&15, k=(lane>>4)*8+j) ----
  bf16x8 qf[2][2];
  #pragma unroll
  for (int mt=0; mt<2; ++mt)
    #pragma unroll
    for (int kt=0; kt<2; ++kt)
      qf[mt][kt] = *(const bf16x8*)&Qg[hoff + (size_t)(row0 + mt*16 + ln)*HD + kt*32 + hi4*8];

  // ---- QK^T -> scores LDS (scaled+masked+clamped) ----
  #pragma unroll
  for (int nt=0; nt<8; ++nt){
    const int kcol = k0w + nt*16 + ln;
    float mval = maskg[b*SEQ + kcol];
    bf16x8 kf0 = *(const bf16x8*)&Kg[hoff + (size_t)kcol*HD +  0 + hi4*8];
    bf16x8 kf1 = *(const bf16x8*)&Kg[hoff + (size_t)kcol*HD + 32 + hi4*8];
    #pragma unroll
    for (int mt=0; mt<2; ++mt){
      f32x4 acc = (f32x4){0.f,0.f,0.f,0.f};
      acc = __builtin_amdgcn_mfma_f32_16x16x32_bf16(qf[mt][0], kf0, acc, 0,0,0);
      acc = __builtin_amdgcn_mfma_f32_16x16x32_bf16(qf[mt][1], kf1, acc, 0,0,0);
      #pragma unroll
      for (int j=0;j<4;++j){
        int q = mt*16 + hi4*4 + j;
        S[q*1024 + kcol] = fmaxf(fmaf(acc[j], SCALE, mval), -10000.f);
      }
    }
  }
  __syncthreads();

  // ---- pull 4 rows into registers (lane owns cols i*64+lane) ----
  float z[4][16];
  #pragma unroll
  for (int r=0;r<4;++r)
    #pragma unroll
    for (int i=0;i<16;++i)
      z[r][i] = S[(w*4+r)*1024 + i*64 + lane];
  __syncthreads();   // all reads done before weight writes alias the buffer

  // ---- sparsemax (even h) / softmax (odd h), write bf16 weights ----
  if ((h&1)==0){
    #pragma unroll
    for (int r=0;r<4;++r){
      float mx = z[r][0];
      #pragma unroll
      for (int i=1;i<16;++i) mx = fmaxf(mx, z[r][i]);
      mx = wmax(mx);
      float lo = mx - 1.0f, bhi = mx;
      for (int it=0; it<12; ++it){
        float mid = 0.5f*(lo+bhi);
        float g = 0.f;
        #pragma unroll
        for (int i=0;i<16;++i) g += fmaxf(z[r][i]-mid, 0.f);
        g = wsum(g);
        if (g >= 1.0f) lo = mid; else bhi = mid;
      }
      float tau = lo;
      #pragma unroll
      for (int nw=0; nw<3; ++nw){            // Newton/Michelot: exact on stabilization
        float cnt=0.f, sm=0.f;
        #pragma unroll
        for (int i=0;i<16;++i){
          bool in = z[r][i] > tau;
          cnt += in ? 1.0f : 0.0f;
          sm  += in ? z[r][i] : 0.0f;
        }
        cnt = wsum(cnt); sm = wsum(sm);
        tau = (sm - 1.0f)/cnt;
      }
      #pragma unroll
      for (int i=0;i<16;++i)
        wstore(Wlds, w*4+r, i*64+lane, fmaxf(z[r][i]-tau, 0.f));
    }
  } else {
    #pragma unroll
    for (int r=0;r<4;++r){
      float mx = z[r][0];
      #pragma unroll
      for (int i=1;i<16;++i) mx = fmaxf(mx, z[r][i]);
      mx = wmax(mx);
      float sm = 0.f;
      #pragma unroll
      for (int i=0;i<16;++i){ z[r][i] = __expf(z[r][i]-mx); sm += z[r][i]; }
      sm = wsum(sm);
      float inv = 1.0f/sm;
      #pragma unroll
      for (int i=0;i<16;++i)
        wstore(Wlds, w*4+r, i*64+lane, z[r][i]*inv);
    }
  }
  __syncthreads();

  // ---- PV: OUT += W[32 x k-slice] @ V[k-slice x 64] per wave ----
  f32x4 oa[2][4];
  #pragma unroll
  for (int mt=0;mt<2;++mt)
    #pragma unroll
    for (int nt=0;nt<4;++nt)
      oa[mt][nt] = (f32x4){0.f,0.f,0.f,0.f};

  #pragma unroll
  for (int kt=0; kt<4; ++kt){
    bf16x8 wa[2];
    #pragma unroll
    for (int mt=0;mt<2;++mt){
      int ch = (w*16 + kt*4 + hi4) ^ ln;
      wa[mt] = *(const bf16x8*)&Wlds[(mt*16+ln)*1024 + ch*8];
    }
    #pragma unroll
    for (int nt=0; nt<4; ++nt){
      bf16x8 vb = *(const bf16x8*)&Vt[(size_t)bh*(HD*SEQ) + (size_t)(nt*16+ln)*SEQ + k0w + kt*32 + hi4*8];
      #pragma unroll
      for (int mt=0;mt<2;++mt)
        oa[mt][nt] = __builtin_amdgcn_mfma_f32_16x16x32_bf16(wa[mt], vb, oa[mt][nt], 0,0,0);
    }
  }
  #pragma unroll
  for (int mt=0;mt<2;++mt)
    #pragma unroll
    for (int nt=0;nt<4;++nt)
      #pragma unroll
      for (int j=0;j<4;++j)
        Pacc[w*2048 + (mt*16 + hi4*4 + j)*64 + nt*16 + ln] = oa[mt][nt][j];
  __syncthreads();

  // ---- reduce 8 partials, write out [B,S,D] fp32 ----
  {
    int q = tid>>4, c4 = (tid&15)<<2;
    f32x4 s = (f32x4){0.f,0.f,0.f,0.f};
    #pragma unroll
    for (int p=0;p<8;++p) s += *(const f32x4*)&Pacc[p*2048 + q*64 + c4];
    *(f32x4*)&outg[((size_t)(b*SEQ + row0 + q))*DM + h*64 + c4] = s;
  }
}

// ---------------- launch ----------------
extern "C" void kernel_launch(void* const* d_in, const int* in_sizes, int n_in,
                              void* d_out, int out_size, void* d_ws, size_t ws_size,
                              hipStream_t stream)
{
  const float* hs   = (const float*)d_in[0];
  const float* Wq   = (const float*)d_in[1];
  const float* bq   = (const float*)d_in[2];
  const float* Wk   = (const float*)d_in[3];
  const float* bk   = (const float*)d_in[4];
  const float* Wv   = (const float*)d_in[5];
  const float* bv   = (const float*)d_in[6];
  const float* mask = (const float*)d_in[7];
  float* out = (float*)d_out;

  char* ws = (char*)d_ws;
  bf16_t* hsb = (bf16_t*)ws;                          // 8 MB
  bf16_t* Wt  = (bf16_t*)(ws + (size_t)( 8u<<20));    // 6 MB
  bf16_t* Qb  = (bf16_t*)(ws + (size_t)(14u<<20));    // 8 MB each
  bf16_t* Kb  = (bf16_t*)(ws + (size_t)(22u<<20));
  bf16_t* Vtb = (bf16_t*)(ws + (size_t)(30u<<20));

  cvt_hs_kernel<<<(NTOK*DM/4 + 255)/256, 256, 0, stream>>>(hs, hsb, NTOK*DM/4);
  cvt_wt_kernel<<<dim3(32,32,3), dim3(32,8), 0, stream>>>(Wq, Wk, Wv, Wt);
  qkv_gemm_kernel<<<dim3(32,8,3), 256, 0, stream>>>(hsb, Wt, bq, bk, bv, Qb, Kb, Vtb);
  attn_mfma_kernel<<<dim3(32,64), 512, 0, stream>>>(Qb, Kb, Vtb, mask, out);
}

// Round 3
// 317.048 us; speedup vs baseline: 2.7655x; 1.0482x over previous
//
#include <hip/hip_runtime.h>
#include <hip/hip_bf16.h>
#include <stdint.h>

#define NH 16
#define HD 64
#define DM 1024
#define NB 4
#define SEQ 1024
#define NTOK (NB*SEQ)
#define SCALE 0.125f

typedef __bf16 bf16_t;
typedef __bf16 bf16x8 __attribute__((ext_vector_type(8)));
typedef __bf16 bf16x4 __attribute__((ext_vector_type(4)));
typedef float f32x4 __attribute__((ext_vector_type(4)));

typedef __attribute__((address_space(3))) unsigned char lds_byte;
typedef __attribute__((address_space(1))) const unsigned char gbl_byte;

__device__ __forceinline__ void glds16(const void* g, void* l){
  __builtin_amdgcn_global_load_lds((gbl_byte*)g, (lds_byte*)l, 16, 0, 0);
}

// ---------------- fp32 -> bf16 convert (hidden_states) ----------------
__global__ void cvt_hs_kernel(const float* __restrict__ in, bf16_t* __restrict__ out, int n4){
  int i = blockIdx.x*256 + threadIdx.x;
  if (i >= n4) return;
  f32x4 v = ((const f32x4*)in)[i];
  bf16x4 o;
  o[0]=(bf16_t)v[0]; o[1]=(bf16_t)v[1]; o[2]=(bf16_t)v[2]; o[3]=(bf16_t)v[3];
  ((bf16x4*)out)[i] = o;
}

// ------------- W transpose + convert: Wt[n][k] = W[k][n] (bf16) -------------
__global__ void cvt_wt_kernel(const float* __restrict__ Wq, const float* __restrict__ Wk,
                              const float* __restrict__ Wv, bf16_t* __restrict__ outbase){
  __shared__ float tile[32][33];
  const float* W = blockIdx.z==0 ? Wq : (blockIdx.z==1 ? Wk : Wv);
  bf16_t* Wt = outbase + (size_t)blockIdx.z * DM * DM;
  int k0 = blockIdx.x*32, n0 = blockIdx.y*32;
  #pragma unroll
  for (int i=0;i<4;i++){
    int r = threadIdx.y + i*8;
    tile[r][threadIdx.x] = W[(size_t)(k0+r)*DM + n0 + threadIdx.x];
  }
  __syncthreads();
  #pragma unroll
  for (int i=0;i<4;i++){
    int r = threadIdx.y + i*8;
    Wt[(size_t)(n0+r)*DM + k0 + threadIdx.x] = (bf16_t)tile[threadIdx.x][r];
  }
}

// ---------------- QKV GEMM: bf16 MFMA, global_load_lds staging ----------------
// Q,K -> [bh][seq][hd] bf16 ; V -> transposed [bh][hd][seq] bf16
__global__ __launch_bounds__(256)
void qkv_gemm_kernel(const bf16_t* __restrict__ Ag, const bf16_t* __restrict__ Wtb,
                     const float* __restrict__ bq, const float* __restrict__ bk, const float* __restrict__ bv,
                     bf16_t* __restrict__ Qb, bf16_t* __restrict__ Kb, bf16_t* __restrict__ Vtb)
{
  __shared__ __align__(16) bf16_t Asm[128*64];
  __shared__ __align__(16) bf16_t Bsm[128*64];
  const int z = blockIdx.z;
  const bf16_t* Btg = Wtb + (size_t)z*DM*DM;
  const float* bias = (z==0)?bq:((z==1)?bk:bv);
  const int m0 = blockIdx.x*128, n0 = blockIdx.y*128;
  const int tid = threadIdx.x, lane = tid&63, w = tid>>6;
  const int wr = w>>1, wc = w&1;
  const int lr = lane&15, hk = (lane>>4)<<3;

  f32x4 acc[4][4];
  #pragma unroll
  for (int a=0;a<4;a++)
    #pragma unroll
    for (int c=0;c<4;c++)
      acc[a][c] = (f32x4){0.f,0.f,0.f,0.f};

  for (int k0=0; k0<DM; k0+=64){
    #pragma unroll
    for (int i=0;i<4;i++){
      int cb = (i<<8) + (tid & 448);       // wave-uniform chunk base (i*256 + w*64)
      int flat = cb + lane;                // per-lane chunk
      int row = flat>>3, kc = (flat&7)<<3;
      glds16(&Ag [(size_t)(m0+row)*DM + k0 + kc], &Asm[cb<<3]);
      glds16(&Btg[(size_t)(n0+row)*DM + k0 + kc], &Bsm[cb<<3]);
    }
    __syncthreads();
    #pragma unroll
    for (int kk=0;kk<2;kk++){
      bf16x8 af[4], bfv[4];
      #pragma unroll
      for (int mf=0;mf<4;mf++)
        af[mf] = *(const bf16x8*)&Asm[((wr*64 + mf*16 + lr)<<6) + (kk<<5) + hk];
      #pragma unroll
      for (int nf=0;nf<4;nf++)
        bfv[nf] = *(const bf16x8*)&Bsm[((wc*64 + nf*16 + lr)<<6) + (kk<<5) + hk];
      #pragma unroll
      for (int mf=0;mf<4;mf++)
        #pragma unroll
        for (int nf=0;nf<4;nf++)
          acc[mf][nf] = __builtin_amdgcn_mfma_f32_16x16x32_bf16(af[mf], bfv[nf], acc[mf][nf], 0, 0, 0);
    }
    __syncthreads();
  }

  const int q4 = (lane>>4)<<2;
  #pragma unroll
  for (int mf=0;mf<4;mf++){
    #pragma unroll
    for (int nf=0;nf<4;nf++){
      int gn = n0 + wc*64 + nf*16 + lr;
      float bsv = bias[gn];
      int hh = gn>>6, hd = gn&63;
      int gm0 = m0 + wr*64 + mf*16 + q4;
      int bb = gm0>>10, sq0 = gm0&1023;
      if (z < 2){
        bf16_t* dst = (z==0)?Qb:Kb;
        #pragma unroll
        for (int j=0;j<4;j++)
          dst[(((size_t)bb*NH + hh)*SEQ + (sq0+j))*HD + hd] = (bf16_t)(acc[mf][nf][j] + bsv);
      } else {
        bf16x4 pk;
        #pragma unroll
        for (int j=0;j<4;j++) pk[j] = (bf16_t)(acc[mf][nf][j] + bsv);
        *(bf16x4*)&Vtb[(((size_t)bb*NH + hh)*HD + hd)*SEQ + sq0] = pk;
      }
    }
  }
}

// ---------------- interleaved 4-row wave reductions ----------------
__device__ __forceinline__ void red4sum(float v[4]){
  #pragma unroll
  for (int m=32;m>=1;m>>=1){
    float t0=__shfl_xor(v[0],m,64), t1=__shfl_xor(v[1],m,64);
    float t2=__shfl_xor(v[2],m,64), t3=__shfl_xor(v[3],m,64);
    v[0]+=t0; v[1]+=t1; v[2]+=t2; v[3]+=t3;
  }
}
__device__ __forceinline__ void red4max(float v[4]){
  #pragma unroll
  for (int m=32;m>=1;m>>=1){
    float t0=__shfl_xor(v[0],m,64), t1=__shfl_xor(v[1],m,64);
    float t2=__shfl_xor(v[2],m,64), t3=__shfl_xor(v[3],m,64);
    v[0]=fmaxf(v[0],t0); v[1]=fmaxf(v[1],t1); v[2]=fmaxf(v[2],t2); v[3]=fmaxf(v[3],t3);
  }
}

// ---------------- fused MFMA attention, 64KB LDS, swapped-operand QK^T ----------------
// Block: one (b,h) x 32 q-rows, 8 waves.
// Phase 1: wave w computes S^T for keys [w*128,(w+1)*128) x all 32 q  (A=K, B=Q)
// Phase 2: wave w*4+r rows sparsemax/softmax, 4-row-interleaved reductions
// Phase 3: wave w -> output tile (q-tile = w>>2, hd-tile = (w&3)*16), full k=1024
__global__ __launch_bounds__(512, 4)
void attn_mfma2_kernel(const bf16_t* __restrict__ Qg, const bf16_t* __restrict__ Kg,
                       const bf16_t* __restrict__ Vt, const float* __restrict__ maskg,
                       float* __restrict__ outg)
{
  __shared__ __align__(16) bf16_t Sb[32*1024];   // 64KB: swizzled scores, then weights
  char* Sbb = (char*)Sb;

  const int bh = blockIdx.y, b = bh>>4, h = bh&15;
  const int row0 = blockIdx.x*32;
  const int tid = threadIdx.x, lane = tid&63, w = tid>>6;
  const int ln = lane&15, hi4 = lane>>4;
  const size_t hoff = (size_t)bh*SEQ*HD;
  const int kbase = w*128;

  // Q fragments (B-operand): rows q = mt*16+ln, k = kt*32 + hi4*8
  bf16x8 qf[2][2];
  #pragma unroll
  for (int mt=0; mt<2; ++mt)
    #pragma unroll
    for (int kt=0; kt<2; ++kt)
      qf[mt][kt] = *(const bf16x8*)&Qg[hoff + (size_t)(row0 + mt*16 + ln)*HD + kt*32 + hi4*8];

  // ---- QK^T (swapped: A=K) -> swizzled bf16 scores ----
  #pragma unroll
  for (int nt=0; nt<8; ++nt){
    const int krow = kbase + nt*16;
    bf16x8 kf0 = *(const bf16x8*)&Kg[hoff + (size_t)(krow+ln)*HD +  0 + hi4*8];
    bf16x8 kf1 = *(const bf16x8*)&Kg[hoff + (size_t)(krow+ln)*HD + 32 + hi4*8];
    f32x4 mv = *(const f32x4*)&maskg[(size_t)b*SEQ + krow + hi4*4];
    #pragma unroll
    for (int mt=0; mt<2; ++mt){
      f32x4 acc = (f32x4){0.f,0.f,0.f,0.f};
      acc = __builtin_amdgcn_mfma_f32_16x16x32_bf16(kf0, qf[mt][0], acc, 0,0,0);
      acc = __builtin_amdgcn_mfma_f32_16x16x32_bf16(kf1, qf[mt][1], acc, 0,0,0);
      // lane holds keys (krow + hi4*4 + j) for q-row (mt*16 + ln)
      bf16x4 pk;
      #pragma unroll
      for (int j=0;j<4;++j)
        pk[j] = (bf16_t)fmaxf(fmaf(acc[j], SCALE, mv[j]), -10000.f);
      const int q = mt*16 + ln;
      const int g = (krow + hi4*4) >> 3;          // 16B granule index
      const int gp = g ^ ln;                      // XOR swizzle by q&15
      *(bf16x4*)(Sbb + q*2048 + gp*16 + (hi4&1)*8) = pk;
    }
  }
  __syncthreads();

  // ---- pull 4 rows to registers: lane owns keys {i*256 + lane*4 + jj} ----
  float z[4][16];
  const int qr = w*4;
  #pragma unroll
  for (int r=0;r<4;++r){
    const int q = qr + r;
    #pragma unroll
    for (int i=0;i<4;++i){
      const int gp = (i*32 + (lane>>1)) ^ (q&15);
      bf16x4 v4 = *(const bf16x4*)(Sbb + q*2048 + gp*16 + (lane&1)*8);
      z[r][i*4+0]=(float)v4[0]; z[r][i*4+1]=(float)v4[1];
      z[r][i*4+2]=(float)v4[2]; z[r][i*4+3]=(float)v4[3];
    }
  }
  __syncthreads();   // reads done before weight writes alias Sb

  // ---- row max (4 rows interleaved) ----
  float mx[4];
  #pragma unroll
  for (int r=0;r<4;++r){
    float m = z[r][0];
    #pragma unroll
    for (int i=1;i<16;++i) m = fmaxf(m, z[r][i]);
    mx[r] = m;
  }
  red4max(mx);

  if ((h&1)==0){
    // ---- sparsemax: 8 bisection + 3 Michelot, rows interleaved ----
    float lo[4], hi_[4];
    #pragma unroll
    for (int r=0;r<4;++r){ lo[r]=mx[r]-1.0f; hi_[r]=mx[r]; }
    for (int it=0; it<8; ++it){
      float mid[4], g4[4];
      #pragma unroll
      for (int r=0;r<4;++r){
        mid[r] = 0.5f*(lo[r]+hi_[r]);
        float g = 0.f;
        #pragma unroll
        for (int i=0;i<16;++i) g += fmaxf(z[r][i]-mid[r], 0.f);
        g4[r] = g;
      }
      red4sum(g4);
      #pragma unroll
      for (int r=0;r<4;++r){
        if (g4[r] >= 1.0f) lo[r] = mid[r]; else hi_[r] = mid[r];
      }
    }
    float tau[4];
    #pragma unroll
    for (int r=0;r<4;++r) tau[r] = lo[r];
    for (int it=0; it<3; ++it){
      float cnt[4], sm[4];
      #pragma unroll
      for (int r=0;r<4;++r){
        float c=0.f, s=0.f;
        #pragma unroll
        for (int i=0;i<16;++i){
          bool in = z[r][i] > tau[r];
          c += in ? 1.0f : 0.0f;
          s += in ? z[r][i] : 0.0f;
        }
        cnt[r]=c; sm[r]=s;
      }
      red4sum(cnt); red4sum(sm);
      #pragma unroll
      for (int r=0;r<4;++r) tau[r] = (sm[r]-1.0f)/cnt[r];
    }
    #pragma unroll
    for (int r=0;r<4;++r)
      #pragma unroll
      for (int i=0;i<16;++i) z[r][i] = fmaxf(z[r][i]-tau[r], 0.f);
  } else {
    // ---- softmax, rows interleaved ----
    float sm[4];
    #pragma unroll
    for (int r=0;r<4;++r){
      float s = 0.f;
      #pragma unroll
      for (int i=0;i<16;++i){ z[r][i] = __expf(z[r][i]-mx[r]); s += z[r][i]; }
      sm[r] = s;
    }
    red4sum(sm);
    #pragma unroll
    for (int r=0;r<4;++r){
      float inv = 1.0f/sm[r];
      #pragma unroll
      for (int i=0;i<16;++i) z[r][i] *= inv;
    }
  }

  // ---- store weights bf16, same swizzle ----
  #pragma unroll
  for (int r=0;r<4;++r){
    const int q = qr + r;
    #pragma unroll
    for (int i=0;i<4;++i){
      bf16x4 pk;
      pk[0]=(bf16_t)z[r][i*4+0]; pk[1]=(bf16_t)z[r][i*4+1];
      pk[2]=(bf16_t)z[r][i*4+2]; pk[3]=(bf16_t)z[r][i*4+3];
      const int gp = (i*32 + (lane>>1)) ^ (q&15);
      *(bf16x4*)(Sbb + q*2048 + gp*16 + (lane&1)*8) = pk;
    }
  }
  __syncthreads();

  // ---- PV: wave -> (q-tile mt, hd-tile), full k=1024, no cross-wave reduce ----
  const int mt = w>>2, hd0 = (w&3)*16;
  const bf16_t* vrow = Vt + (size_t)bh*HD*SEQ + (size_t)(hd0+ln)*SEQ;
  const char* wrow = Sbb + (mt*16+ln)*2048;
  f32x4 o0 = (f32x4){0.f,0.f,0.f,0.f}, o1 = (f32x4){0.f,0.f,0.f,0.f};
  #pragma unroll
  for (int kt=0; kt<32; kt+=2){
    bf16x8 wa0 = *(const bf16x8*)(wrow + ((((kt+0)*4+hi4) ^ ln)<<4));
    bf16x8 vb0 = *(const bf16x8*)&vrow[(kt+0)*32 + hi4*8];
    o0 = __builtin_amdgcn_mfma_f32_16x16x32_bf16(wa0, vb0, o0, 0,0,0);
    bf16x8 wa1 = *(const bf16x8*)(wrow + ((((kt+1)*4+hi4) ^ ln)<<4));
    bf16x8 vb1 = *(const bf16x8*)&vrow[(kt+1)*32 + hi4*8];
    o1 = __builtin_amdgcn_mfma_f32_16x16x32_bf16(wa1, vb1, o1, 0,0,0);
  }
  o0 += o1;
  #pragma unroll
  for (int j=0;j<4;++j)
    outg[(size_t)(b*SEQ + row0 + mt*16 + hi4*4 + j)*DM + h*64 + hd0 + ln] = o0[j];
}

// ---------------- launch ----------------
extern "C" void kernel_launch(void* const* d_in, const int* in_sizes, int n_in,
                              void* d_out, int out_size, void* d_ws, size_t ws_size,
                              hipStream_t stream)
{
  const float* hs   = (const float*)d_in[0];
  const float* Wq   = (const float*)d_in[1];
  const float* bq   = (const float*)d_in[2];
  const float* Wk   = (const float*)d_in[3];
  const float* bk   = (const float*)d_in[4];
  const float* Wv   = (const float*)d_in[5];
  const float* bv   = (const float*)d_in[6];
  const float* mask = (const float*)d_in[7];
  float* out = (float*)d_out;

  char* ws = (char*)d_ws;
  bf16_t* hsb = (bf16_t*)ws;                          // 8 MB
  bf16_t* Wt  = (bf16_t*)(ws + (size_t)( 8u<<20));    // 6 MB
  bf16_t* Qb  = (bf16_t*)(ws + (size_t)(14u<<20));    // 8 MB each
  bf16_t* Kb  = (bf16_t*)(ws + (size_t)(22u<<20));
  bf16_t* Vtb = (bf16_t*)(ws + (size_t)(30u<<20));

  cvt_hs_kernel<<<(NTOK*DM/4 + 255)/256, 256, 0, stream>>>(hs, hsb, NTOK*DM/4);
  cvt_wt_kernel<<<dim3(32,32,3), dim3(32,8), 0, stream>>>(Wq, Wk, Wv, Wt);
  qkv_gemm_kernel<<<dim3(32,8,3), 256, 0, stream>>>(hsb, Wt, bq, bk, bv, Qb, Kb, Vtb);
  attn_mfma2_kernel<<<dim3(32,64), 512, 0, stream>>>(Qb, Kb, Vtb, mask, out);
}